// Round 2
// baseline (353.407 us; speedup 1.0000x reference)
//
#include <hip/hip_runtime.h>
#include <cstdint>
#include <cstddef>

// Problem dims (fixed by the reference)
#define MDIM 16384    // B_SZ * L
#define HDIM 1024
#define PDIM 1024
#define LSEQ 4096
#define BSZ  4
#define CHUNK 64
#define NCHUNK 64     // LSEQ / CHUNK
#define NBU  2048     // 2*PDIM (interleaved re/im)

typedef float   floatx4  __attribute__((ext_vector_type(4)));
typedef __bf16  bf16x8   __attribute__((ext_vector_type(8)));
typedef unsigned short u16;
typedef unsigned short u16x8 __attribute__((ext_vector_type(8)));

// fp32 -> bf16 round-to-nearest-even
__device__ __forceinline__ u16 f2bf(float f) {
    union { float f; uint32_t u; } v; v.f = f;
    return (u16)((v.u + 0x7fffu + ((v.u >> 16) & 1u)) >> 16);
}
__device__ __forceinline__ float bfu2f(uint32_t bits16) {
    union { float f; uint32_t u; } v; v.u = bits16 << 16; return v.f;
}
__device__ __forceinline__ bf16x8 ldfrag(const u16* p) {
    return __builtin_bit_cast(bf16x8, *(const u16x8*)p);
}
// async global->LDS, 16B per lane; LDS deposit = wave-uniform base + lane*16
__device__ __forceinline__ void gload16(const u16* g, u16* l) {
    __builtin_amdgcn_global_load_lds(
        (const __attribute__((address_space(1))) uint32_t*)g,
        (__attribute__((address_space(3))) uint32_t*)l, 16, 0, 0);
}

// raw barrier: compiler memory fence + sched fence + s_barrier.
// NOT __syncthreads (that drains vmcnt(0) and kills the load pipeline).
#define BARRIER() do { \
    asm volatile("" ::: "memory"); \
    __builtin_amdgcn_sched_barrier(0); \
    __builtin_amdgcn_s_barrier(); \
    __builtin_amdgcn_sched_barrier(0); \
    asm volatile("" ::: "memory"); \
} while (0)

// counted vmcnt wait, pinned against compiler motion
#define WAITV(N_) do { \
    __builtin_amdgcn_sched_barrier(0); \
    asm volatile("s_waitcnt vmcnt(" #N_ ")" ::: "memory"); \
    __builtin_amdgcn_sched_barrier(0); \
} while (0)

// ---------------------------------------------------------------------------
// 256x256 8-phase GEMM core (BK=64, 8 waves = 2M x 4N, 128x64 C per wave).
// LDS: double-buffered A[256][64] + B[256][64] bf16 = 128 KiB.
// Schedule per K-tile (4 phases, template order: ds-load -> stage -> barrier
// -> lgkm -> MFMA -> barrier). Staging of tile t+1 issued across tile t's
// phases in group order B01,B23,A02,A13; counted vmcnt: (2) at tile end
// (drains B01/B23/A02, A13 stays in flight), (4) at next P1 (drains A13).
// Never vmcnt(0) mid-loop. bFa/bFb both held in regs -> P3 has no ds_reads.
// LDS XOR swizzle: 16B chunk index ^ (row&7), applied on the global source
// address (deposit is linear) and on the ds_read address.
// ---------------------------------------------------------------------------
template<int MH>
__device__ __forceinline__ void ldA(const u16* buf, int aBase, int c0, int c1,
                                    bf16x8 (&aF)[4][2]) {
    #pragma unroll
    for (int mf = 0; mf < 4; ++mf) {
        const u16* p = buf + aBase + (MH * 4 + mf) * 1024;
        aF[mf][0] = ldfrag(p + c0);
        aF[mf][1] = ldfrag(p + c1);
    }
}
template<int NH>
__device__ __forceinline__ void ldB(const u16* buf, int bBase, int c0, int c1,
                                    bf16x8 (&bF)[2][2]) {
    #pragma unroll
    for (int j = 0; j < 2; ++j) {
        const u16* p = buf + bBase + (NH * 2 + j) * 1024;
        bF[j][0] = ldfrag(p + c0);
        bF[j][1] = ldfrag(p + c1);
    }
}
template<int MH, int NH>
__device__ __forceinline__ void doMFMA(bf16x8 (&aF)[4][2], bf16x8 (&bF)[2][2],
                                       floatx4 (&acc)[8][4]) {
    __builtin_amdgcn_s_setprio(1);
    #pragma unroll
    for (int s = 0; s < 2; ++s)
        #pragma unroll
        for (int mf = 0; mf < 4; ++mf)
            #pragma unroll
            for (int j = 0; j < 2; ++j)
                acc[MH * 4 + mf][NH * 2 + j] =
                    __builtin_amdgcn_mfma_f32_16x16x32_bf16(
                        aF[mf][s], bF[j][s], acc[MH * 4 + mf][NH * 2 + j],
                        0, 0, 0);
    __builtin_amdgcn_s_setprio(0);
}

template<int KD>
__device__ __forceinline__ void gemm256_core(
    const u16* __restrict__ A, const u16* __restrict__ B,
    int m0, int n0, u16* smem, floatx4 (&acc)[8][4])
{
    const int tid  = threadIdx.x;
    const int wave = tid >> 6, lane = tid & 63;
    const int lrow = lane & 15, lq = lane >> 4;
    const int wm = wave >> 2, wn = wave & 3;
    const int axr = lrow & 7;
    const int c0 = (lq ^ axr) * 8;          // kstep 0: 16B chunk offset (u16)
    const int c1 = ((4 + lq) ^ axr) * 8;    // kstep 1
    const int aBase = (wm * 128 + lrow) * 64;
    const int bBase = (wn * 64  + lrow) * 64;
    // staging: thread t stages row i*64 + (t>>3), source chunk (t&7)^(row&7)
    const int srow = tid >> 3;              // 0..63
    const int schk = (tid & 7) ^ (srow & 7);
    const u16* aptr = A + (size_t)(m0 + srow) * KD + schk * 8;
    const u16* bptr = B + (size_t)(n0 + srow) * KD + schk * 8;
    const int lw = wave * 512;              // per-wave LDS deposit offset

    u16* curA = smem;          u16* curB = smem + 16384;
    u16* nxtA = smem + 32768;  u16* nxtB = smem + 49152;

    bf16x8 aF[4][2], bFa[2][2], bFb[2][2];

    #define STG2(p_, d_, i0_, i1_, k_) do { \
        gload16((p_) + (size_t)(i0_) * 64 * KD + (k_), (d_) + (i0_) * 4096 + lw); \
        gload16((p_) + (size_t)(i1_) * 64 * KD + (k_), (d_) + (i1_) * 4096 + lw); \
    } while (0)

    // prologue: stage tile 0 -> cur in steady-state order; A13 stays in flight
    STG2(bptr, curB, 0, 1, 0);
    STG2(bptr, curB, 2, 3, 0);
    STG2(aptr, curA, 0, 2, 0);
    STG2(aptr, curA, 1, 3, 0);
    WAITV(2);
    BARRIER();

    const int NT = KD / 64;
    for (int t = 0; t < NT; ++t) {
        const int kn = (t + 1) * 64;
        const bool hn = (t + 1 < NT);

        // ---- P0: quadrant (0,0)
        ldA<0>(curA, aBase, c0, c1, aF);
        ldB<0>(curB, bBase, c0, c1, bFa);
        if (hn) STG2(bptr, nxtB, 0, 1, kn);
        BARRIER();
        doMFMA<0, 0>(aF, bFa, acc);
        BARRIER();

        // ---- P1: quadrant (0,1) — reuse aF, load bFb
        ldB<1>(curB, bBase, c0, c1, bFb);
        if (hn) STG2(bptr, nxtB, 2, 3, kn);
        BARRIER();
        doMFMA<0, 1>(aF, bFb, acc);
        if (hn) { WAITV(4); } else { WAITV(0); }   // drain this tile's A13
        BARRIER();

        // ---- P2: quadrant (1,1) — reuse bFb, load aF half 1
        ldA<1>(curA, aBase, c0, c1, aF);
        if (hn) STG2(aptr, nxtA, 0, 2, kn);
        BARRIER();
        doMFMA<1, 1>(aF, bFb, acc);
        BARRIER();

        // ---- P3: quadrant (1,0) — reuse aF and held bFa, no ds_reads
        if (hn) STG2(aptr, nxtA, 1, 3, kn);
        doMFMA<1, 0>(aF, bFa, acc);
        if (hn) WAITV(2);                 // drain next tile's B01/B23/A02
        BARRIER();                        // tile boundary: nxt visible to all

        u16* tA = curA; curA = nxtA; nxtA = tA;
        u16* tB = curB; curB = nxtB; nxtB = tB;
    }
    #undef STG2
}

// ---------------------------------------------------------------------------
// Kernel: Bu = Ubf @ Bcomb^T  (M=16384, N=2048, K=1024), output bf16.
// Grid 512 blocks x 512 thr. Epilogue: wave-private LDS repack (XOR-swizzled,
// no barriers) -> fully coalesced 16B stores.
// ---------------------------------------------------------------------------
__global__ __launch_bounds__(512, 2) void gemm_bu_k(
    const u16* __restrict__ A, const u16* __restrict__ B, u16* __restrict__ O)
{
    __shared__ __align__(16) u16 smem[65536];   // 128 KiB
    floatx4 acc[8][4] = {};
    const int d = blockIdx.x;
    const int xcd = d & 7, s = d >> 3;               // s: 0..63
    const int m0 = (xcd * 8 + (s >> 3)) * 256;       // 8 m-tiles per XCD band
    const int n0 = (s & 7) * 256;
    gemm256_core<HDIM>(A, B, m0, n0, smem, acc);

    const int tid = threadIdx.x, wave = tid >> 6, lane = tid & 63;
    const int lrow = lane & 15, lq = lane >> 4;
    const int wm = wave >> 2, wn = wave & 3;
    u16* lwp = smem + wave * 4096;                   // 8 KiB per wave
    #pragma unroll
    for (int mh = 0; mh < 2; ++mh) {
        // write 64x64 wave block, chunk XOR-swizzled (conflict-free readback)
        #pragma unroll
        for (int mfl = 0; mfl < 4; ++mfl)
            #pragma unroll
            for (int nf = 0; nf < 4; ++nf)
                #pragma unroll
                for (int r = 0; r < 4; ++r) {
                    int rowl = mfl * 16 + lq * 4 + r;              // 0..63
                    int cpos = (nf * 2 + (lrow >> 3)) ^ (rowl & 7);
                    lwp[rowl * 64 + cpos * 8 + (lrow & 7)] =
                        f2bf(acc[mh * 4 + mfl][nf][r]);
                }
        // readback: lane = row, 8 x 16B coalesced stores
        int grow = m0 + wm * 128 + mh * 64 + lane;
        #pragma unroll
        for (int j = 0; j < 8; ++j) {
            int cpos = j ^ (lane & 7);
            *(u16x8*)(O + (size_t)grow * NBU + n0 + wn * 64 + j * 8) =
                *(const u16x8*)(lwp + lane * 64 + cpos * 8);
        }
    }
}

// ---------------------------------------------------------------------------
// Kernel: out = Re(C x) + D.*u  (M=16384, N=1024, K=2048), output fp32.
// Grid 256 blocks x 512 thr (exactly 1 block/CU).
// ---------------------------------------------------------------------------
__global__ __launch_bounds__(512, 2) void gemm_out_k(
    const u16* __restrict__ A, const u16* __restrict__ B,
    const float* __restrict__ Dv, const u16* __restrict__ Ubf,
    float* __restrict__ O)
{
    __shared__ __align__(16) u16 smem[65536];   // 128 KiB
    floatx4 acc[8][4] = {};
    const int d = blockIdx.x;
    const int xcd = d & 7, s = d >> 3;               // s: 0..31
    const int m0 = (xcd * 8 + (s >> 2)) * 256;
    const int n0 = (s & 3) * 256;
    gemm256_core<NBU>(A, B, m0, n0, smem, acc);

    const int tid = threadIdx.x, wave = tid >> 6, lane = tid & 63;
    const int lrow = lane & 15, lq = lane >> 4;
    const int wm = wave >> 2, wn = wave & 3;
    #pragma unroll
    for (int nf = 0; nf < 4; ++nf) {
        int col = n0 + wn * 64 + nf * 16 + lrow;
        float dval = Dv[col];
        #pragma unroll
        for (int mf = 0; mf < 8; ++mf)
            #pragma unroll
            for (int r = 0; r < 4; ++r) {
                int row = m0 + wm * 128 + mf * 16 + lq * 4 + r;
                size_t o = (size_t)row * HDIM + col;
                O[o] = acc[mf][nf][r] + dval * bfu2f(Ubf[o]);
            }
    }
}

// ---------------------------------------------------------------------------
// Merged prep kernel (single launch): band 0 = U->bf16 (8192 blocks),
// band 1 = Bcomb (1024 blocks), band 2 = Bcbf (1024 blocks).
// ---------------------------------------------------------------------------
__global__ __launch_bounds__(256) void prep_all(
    const float* __restrict__ U, u16* __restrict__ Ubf,
    const float* __restrict__ Bre, const float* __restrict__ Bim,
    const float* __restrict__ gamma_log, u16* __restrict__ Bcomb,
    const float* __restrict__ Cre, const float* __restrict__ Cim,
    u16* __restrict__ Bcbf)
{
    const int bid = blockIdx.x;
    if (bid < 8192) {
        size_t i = ((size_t)bid * 256 + threadIdx.x) * 8;
        float4 a = *(const float4*)(U + i);
        float4 b = *(const float4*)(U + i + 4);
        u16x8 w;
        w[0]=f2bf(a.x); w[1]=f2bf(a.y); w[2]=f2bf(a.z); w[3]=f2bf(a.w);
        w[4]=f2bf(b.x); w[5]=f2bf(b.y); w[6]=f2bf(b.z); w[7]=f2bf(b.w);
        *(u16x8*)(Ubf + i) = w;
    } else if (bid < 9216) {
        int t = (bid - 8192) * 256 + threadIdx.x;      // 0 .. 262143
        int n = t >> 7;
        int h = (t & 127) * 8;
        int p = n >> 1, sflag = n & 1;
        const float* src = (sflag ? Bim : Bre) + (size_t)p * HDIM + h;
        float g = expf(gamma_log[p]);
        float4 a = *(const float4*)src;
        float4 b = *(const float4*)(src + 4);
        u16x8 w;
        w[0]=f2bf(a.x*g); w[1]=f2bf(a.y*g); w[2]=f2bf(a.z*g); w[3]=f2bf(a.w*g);
        w[4]=f2bf(b.x*g); w[5]=f2bf(b.y*g); w[6]=f2bf(b.z*g); w[7]=f2bf(b.w*g);
        *(u16x8*)(Bcomb + (size_t)n * HDIM + h) = w;
    } else {
        int t = (bid - 9216) * 256 + threadIdx.x;      // 0 .. 262143
        int h = t >> 8;
        int k = (t & 255) * 4;
        float4 cr = *(const float4*)(Cre + (size_t)h * PDIM + k);
        float4 ci = *(const float4*)(Cim + (size_t)h * PDIM + k);
        u16x8 w;
        w[0]=f2bf(cr.x); w[1]=f2bf(-ci.x);
        w[2]=f2bf(cr.y); w[3]=f2bf(-ci.y);
        w[4]=f2bf(cr.z); w[5]=f2bf(-ci.z);
        w[6]=f2bf(cr.w); w[7]=f2bf(-ci.w);
        *(u16x8*)(Bcbf + (size_t)h * NBU + 2 * k) = w;
    }
}

// ---------------------------------------------------------------------------
// Scan pass A: per-chunk local end states (bf16 Bu in, fp32 state out).
// ---------------------------------------------------------------------------
__global__ __launch_bounds__(256) void scan_passA(
    const uint32_t* __restrict__ BuC,
    const float* __restrict__ nu_log, const float* __restrict__ theta_log,
    float* __restrict__ endC)
{
    int tid = blockIdx.x * 256 + threadIdx.x;           // 0 .. 131071
    int p0 = (tid & 511) * 2;
    int c  = (tid >> 9) & (NCHUNK - 1);
    int b  = tid >> 15;
    float nu0 = expf(nu_log[p0]),     th0 = expf(theta_log[p0]);
    float nu1 = expf(nu_log[p0 + 1]), th1 = expf(theta_log[p0 + 1]);
    float el0 = expf(-nu0), el1 = expf(-nu1);
    float lr0 = el0 * cosf(th0), li0 = el0 * sinf(th0);
    float lr1 = el1 * cosf(th1), li1 = el1 * sinf(th1);
    const uint32_t* src = BuC + (size_t)(b * LSEQ + c * CHUNK) * PDIM + p0;
    float xr0 = 0.f, xi0 = 0.f, xr1 = 0.f, xi1 = 0.f;
    #pragma unroll 8
    for (int t = 0; t < CHUNK; ++t) {
        uint2 v = *(const uint2*)(src + (size_t)t * PDIM);
        float br0 = bfu2f(v.x & 0xffffu), bi0 = bfu2f(v.x >> 16);
        float br1 = bfu2f(v.y & 0xffffu), bi1 = bfu2f(v.y >> 16);
        float nr0 = fmaf(lr0, xr0, fmaf(-li0, xi0, br0));
        float ni0 = fmaf(lr0, xi0, fmaf(li0, xr0, bi0));
        float nr1 = fmaf(lr1, xr1, fmaf(-li1, xi1, br1));
        float ni1 = fmaf(lr1, xi1, fmaf(li1, xr1, bi1));
        xr0 = nr0; xi0 = ni0; xr1 = nr1; xi1 = ni1;
    }
    float4 e; e.x = xr0; e.y = xi0; e.z = xr1; e.w = xi1;
    *(float4*)(endC + (((size_t)b * NCHUNK + c) * PDIM + p0) * 2) = e;
}

// ---------------------------------------------------------------------------
// Scan pass B: carry prefix across chunks.
// ---------------------------------------------------------------------------
__global__ __launch_bounds__(256) void scan_passB(
    const float* __restrict__ endC,
    const float* __restrict__ nu_log, const float* __restrict__ theta_log,
    float* __restrict__ carryC)
{
    int tid = blockIdx.x * 256 + threadIdx.x;           // 0 .. 2047
    int p0 = (tid & 511) * 2;
    int b  = tid >> 9;
    float nu0 = expf(nu_log[p0]),     th0 = expf(theta_log[p0]);
    float nu1 = expf(nu_log[p0 + 1]), th1 = expf(theta_log[p0 + 1]);
    float e0 = expf(-nu0 * (float)CHUNK), a0 = th0 * (float)CHUNK;
    float e1 = expf(-nu1 * (float)CHUNK), a1 = th1 * (float)CHUNK;
    float Lr0 = e0 * cosf(a0), Li0 = e0 * sinf(a0);
    float Lr1 = e1 * cosf(a1), Li1 = e1 * sinf(a1);
    float gr0 = 0.f, gi0 = 0.f, gr1 = 0.f, gi1 = 0.f;
    for (int g = 0; g < 8; ++g) {
        float4 e[8];
        #pragma unroll
        for (int j = 0; j < 8; ++j)
            e[j] = *(const float4*)(endC + (((size_t)b * NCHUNK + g * 8 + j) * PDIM + p0) * 2);
        #pragma unroll
        for (int j = 0; j < 8; ++j) {
            size_t idx = (((size_t)b * NCHUNK + g * 8 + j) * PDIM + p0) * 2;
            float4 go; go.x = gr0; go.y = gi0; go.z = gr1; go.w = gi1;
            *(float4*)(carryC + idx) = go;
            float nr0 = fmaf(Lr0, gr0, fmaf(-Li0, gi0, e[j].x));
            float ni0 = fmaf(Lr0, gi0, fmaf(Li0, gr0, e[j].y));
            float nr1 = fmaf(Lr1, gr1, fmaf(-Li1, gi1, e[j].z));
            float ni1 = fmaf(Lr1, gi1, fmaf(Li1, gr1, e[j].w));
            gr0 = nr0; gi0 = ni0; gr1 = nr1; gi1 = ni1;
        }
    }
}

// ---------------------------------------------------------------------------
// Scan pass C: re-scan each chunk from its entering state; x in place.
// ---------------------------------------------------------------------------
__global__ __launch_bounds__(256) void scan_passC(
    uint32_t* __restrict__ BuC,
    const float* __restrict__ nu_log, const float* __restrict__ theta_log,
    const float* __restrict__ carryC)
{
    int tid = blockIdx.x * 256 + threadIdx.x;           // 0 .. 131071
    int p0 = (tid & 511) * 2;
    int c  = (tid >> 9) & (NCHUNK - 1);
    int b  = tid >> 15;
    float nu0 = expf(nu_log[p0]),     th0 = expf(theta_log[p0]);
    float nu1 = expf(nu_log[p0 + 1]), th1 = expf(theta_log[p0 + 1]);
    float el0 = expf(-nu0), el1 = expf(-nu1);
    float lr0 = el0 * cosf(th0), li0 = el0 * sinf(th0);
    float lr1 = el1 * cosf(th1), li1 = el1 * sinf(th1);
    float4 g = *(const float4*)(carryC + (((size_t)b * NCHUNK + c) * PDIM + p0) * 2);
    float xr0 = g.x, xi0 = g.y, xr1 = g.z, xi1 = g.w;
    uint32_t* ptr = BuC + (size_t)(b * LSEQ + c * CHUNK) * PDIM + p0;
    #pragma unroll 8
    for (int t = 0; t < CHUNK; ++t) {
        uint32_t* q = ptr + (size_t)t * PDIM;
        uint2 v = *(const uint2*)q;
        float br0 = bfu2f(v.x & 0xffffu), bi0 = bfu2f(v.x >> 16);
        float br1 = bfu2f(v.y & 0xffffu), bi1 = bfu2f(v.y >> 16);
        float nr0 = fmaf(lr0, xr0, fmaf(-li0, xi0, br0));
        float ni0 = fmaf(lr0, xi0, fmaf(li0, xr0, bi0));
        float nr1 = fmaf(lr1, xr1, fmaf(-li1, xi1, br1));
        float ni1 = fmaf(lr1, xi1, fmaf(li1, xr1, bi1));
        xr0 = nr0; xi0 = ni0; xr1 = nr1; xi1 = ni1;
        uint2 o;
        o.x = (uint32_t)f2bf(xr0) | ((uint32_t)f2bf(xi0) << 16);
        o.y = (uint32_t)f2bf(xr1) | ((uint32_t)f2bf(xi1) << 16);
        *(uint2*)q = o;
    }
}

// ---------------------------------------------------------------------------
extern "C" void kernel_launch(void* const* d_in, const int* in_sizes, int n_in,
                              void* d_out, int out_size, void* d_ws, size_t ws_size,
                              hipStream_t stream)
{
    (void)in_sizes; (void)n_in; (void)out_size; (void)ws_size;
    const float* U         = (const float*)d_in[0];
    const float* nu_log    = (const float*)d_in[1];
    const float* theta_log = (const float*)d_in[2];
    const float* B_re      = (const float*)d_in[3];
    const float* B_im      = (const float*)d_in[4];
    const float* C_re      = (const float*)d_in[5];
    const float* C_im      = (const float*)d_in[6];
    const float* Dv        = (const float*)d_in[7];
    const float* gamma_log = (const float*)d_in[8];
    float* out = (float*)d_out;

    // workspace layout (bytes), 256B aligned
    char* ws = (char*)d_ws;
    u16*   BuC    = (u16*)ws;                                   // 64 MB
    u16*   Ubf    = (u16*)(ws + (size_t)64 * 1024 * 1024);      // 32 MB
    u16*   Bcomb  = (u16*)(ws + (size_t)96 * 1024 * 1024);      // 4 MB
    u16*   Bcbf   = (u16*)(ws + (size_t)100 * 1024 * 1024);     // 4 MB
    float* endC   = (float*)(ws + (size_t)104 * 1024 * 1024);   // 2 MB
    float* carryC = (float*)(ws + (size_t)106 * 1024 * 1024);   // 2 MB

    prep_all<<<8192 + 1024 + 1024, 256, 0, stream>>>(
        U, Ubf, B_re, B_im, gamma_log, Bcomb, C_re, C_im, Bcbf);

    gemm_bu_k<<<512, 512, 0, stream>>>(Ubf, Bcomb, BuC);

    scan_passA<<<(BSZ * NCHUNK * PDIM / 2) / 256, 256, 0, stream>>>(
        (const uint32_t*)BuC, nu_log, theta_log, endC);
    scan_passB<<<(BSZ * PDIM / 2) / 256, 256, 0, stream>>>(endC, nu_log, theta_log, carryC);
    scan_passC<<<(BSZ * NCHUNK * PDIM / 2) / 256, 256, 0, stream>>>(
        (uint32_t*)BuC, nu_log, theta_log, carryC);

    gemm_out_k<<<256, 512, 0, stream>>>(BuC, Bcbf, Dv, Ubf, out);
}

// Round 3
// 351.234 us; speedup vs baseline: 1.0062x; 1.0062x over previous
//
#include <hip/hip_runtime.h>
#include <cstdint>
#include <cstddef>

// Problem dims (fixed by the reference)
#define MDIM 16384    // B_SZ * L
#define HDIM 1024
#define PDIM 1024
#define LSEQ 4096
#define BSZ  4
#define CHUNK 64
#define NCHUNK 64     // LSEQ / CHUNK
#define NBU  2048     // 2*PDIM (interleaved re/im)

typedef float   floatx4  __attribute__((ext_vector_type(4)));
typedef __bf16  bf16x8   __attribute__((ext_vector_type(8)));
typedef unsigned short u16;
typedef unsigned short u16x8 __attribute__((ext_vector_type(8)));

// fp32 -> bf16 round-to-nearest-even
__device__ __forceinline__ u16 f2bf(float f) {
    union { float f; uint32_t u; } v; v.f = f;
    return (u16)((v.u + 0x7fffu + ((v.u >> 16) & 1u)) >> 16);
}
__device__ __forceinline__ float bfu2f(uint32_t bits16) {
    union { float f; uint32_t u; } v; v.u = bits16 << 16; return v.f;
}
__device__ __forceinline__ bf16x8 ldfrag(const u16* p) {
    return __builtin_bit_cast(bf16x8, *(const u16x8*)p);
}
// async global->LDS, 16B per lane; LDS deposit = wave-uniform base + lane*16
__device__ __forceinline__ void gload16(const u16* g, u16* l) {
    __builtin_amdgcn_global_load_lds(
        (const __attribute__((address_space(1))) uint32_t*)g,
        (__attribute__((address_space(3))) uint32_t*)l, 16, 0, 0);
}

// raw barrier: compiler memory fence + sched fence + s_barrier.
#define BARRIER() do { \
    asm volatile("" ::: "memory"); \
    __builtin_amdgcn_sched_barrier(0); \
    __builtin_amdgcn_s_barrier(); \
    __builtin_amdgcn_sched_barrier(0); \
    asm volatile("" ::: "memory"); \
} while (0)

// counted vmcnt wait, pinned against compiler motion
#define WAITV(N_) do { \
    __builtin_amdgcn_sched_barrier(0); \
    asm volatile("s_waitcnt vmcnt(" #N_ ")" ::: "memory"); \
    __builtin_amdgcn_sched_barrier(0); \
} while (0)

// ===========================================================================
// PART 1: round-0 verified 128x128 core (m97 structure) — used by gemm_bu_k.
// ===========================================================================
template<int KD>
__device__ __forceinline__ void gemm_core128(
    const u16* __restrict__ A, const u16* __restrict__ B,
    int m0, int n0, u16* sA, u16* sB, floatx4 acc[4][4])
{
    const int tid  = threadIdx.x;
    const int wave = tid >> 6, lane = tid & 63;
    const int lrow = lane & 15, lq = lane >> 4;
    const int wm = (wave >> 1) * 64, wn = (wave & 1) * 64;
    const int srow   = lane >> 3;            // 0..7 row within 8-row group
    const int schunk = (lane & 7) ^ srow;    // swizzled logical 16B chunk

    const u16* aptr = A + (size_t)(m0 + wave * 32 + srow) * KD + schunk * 8;
    const u16* bptr = B + (size_t)(n0 + wave * 32 + srow) * KD + schunk * 8;
    u16* sAw = sA + wave * 32 * 64;
    u16* sBw = sB + wave * 32 * 64;

    for (int k0 = 0; k0 < KD; k0 += 64) {
        #pragma unroll
        for (int i = 0; i < 4; ++i) {
            gload16(aptr + (size_t)i * 8 * KD + k0, sAw + i * 8 * 64);
            gload16(bptr + (size_t)i * 8 * KD + k0, sBw + i * 8 * 64);
        }
        __syncthreads();
        #pragma unroll
        for (int s = 0; s < 2; ++s) {
            bf16x8 af[4], bfr[4];
            #pragma unroll
            for (int mt = 0; mt < 4; ++mt) {
                int r = wm + mt * 16 + lrow;
                af[mt] = ldfrag(sA + r * 64 + (((s * 4 + lq) ^ (r & 7)) * 8));
            }
            #pragma unroll
            for (int nt = 0; nt < 4; ++nt) {
                int r = wn + nt * 16 + lrow;
                bfr[nt] = ldfrag(sB + r * 64 + (((s * 4 + lq) ^ (r & 7)) * 8));
            }
            #pragma unroll
            for (int mt = 0; mt < 4; ++mt)
                #pragma unroll
                for (int nt = 0; nt < 4; ++nt)
                    acc[mt][nt] = __builtin_amdgcn_mfma_f32_16x16x32_bf16(
                        af[mt], bfr[nt], acc[mt][nt], 0, 0, 0);
        }
        __syncthreads();
    }
}

// ===========================================================================
// PART 2: 256x256 deep-pipelined 8-phase core (derived counted waits) —
// used by gemm_out_k.  8 waves = 2M x 4N, per-wave C = 128x64, BK=64.
// LDS: 2 x (A[256][64] + B[256][64]) bf16 = 128 KiB.
// Stage stream per tile u: {B(u+1)h1 @P0, B(u+2)h0 @P2, A(u+2)h0+h1 @P3};
// ONE counted wait per tile: vmcnt(6) at P3 (3 half-tiles stay in flight).
// WAR safety: B(u+2) deposits (parity-u buf) issued at P2, after all waves'
// last B ds-read (P1) passed a barrier; A(u+2) at P3, after last A read (P2).
// ===========================================================================
template<int MH>
__device__ __forceinline__ void ldA(const u16* buf, int aBase, int c0, int c1,
                                    bf16x8 (&aF)[4][2]) {
    #pragma unroll
    for (int mf = 0; mf < 4; ++mf) {
        const u16* p = buf + aBase + (MH * 4 + mf) * 1024;
        aF[mf][0] = ldfrag(p + c0);
        aF[mf][1] = ldfrag(p + c1);
    }
}
template<int NH>
__device__ __forceinline__ void ldB(const u16* buf, int bBase, int c0, int c1,
                                    bf16x8 (&bF)[2][2]) {
    #pragma unroll
    for (int j = 0; j < 2; ++j) {
        const u16* p = buf + bBase + (NH * 2 + j) * 1024;
        bF[j][0] = ldfrag(p + c0);
        bF[j][1] = ldfrag(p + c1);
    }
}
template<int MH, int NH>
__device__ __forceinline__ void doMFMA(bf16x8 (&aF)[4][2], bf16x8 (&bF)[2][2],
                                       floatx4 (&acc)[8][4]) {
    __builtin_amdgcn_s_setprio(1);
    #pragma unroll
    for (int s = 0; s < 2; ++s)
        #pragma unroll
        for (int mf = 0; mf < 4; ++mf)
            #pragma unroll
            for (int j = 0; j < 2; ++j)
                acc[MH * 4 + mf][NH * 2 + j] =
                    __builtin_amdgcn_mfma_f32_16x16x32_bf16(
                        aF[mf][s], bF[j][s], acc[MH * 4 + mf][NH * 2 + j],
                        0, 0, 0);
    __builtin_amdgcn_s_setprio(0);
}

template<int KD>
__device__ __forceinline__ void gemm256_deep(
    const u16* __restrict__ A, const u16* __restrict__ B,
    int m0, int n0, u16* smem, floatx4 (&acc)[8][4])
{
    const int tid  = threadIdx.x;
    const int wave = tid >> 6, lane = tid & 63;
    const int lrow = lane & 15, lq = lane >> 4;
    const int wm = wave >> 2, wn = wave & 3;
    const int axr = lrow & 7;
    const int c0 = (lq ^ axr) * 8;          // kstep 0: 16B chunk offset (u16)
    const int c1 = ((4 + lq) ^ axr) * 8;    // kstep 1
    const int aBase = (wm * 128 + lrow) * 64;
    const int bBase = (wn * 64  + lrow) * 64;
    // staging: thread t stages row g*64 + (t>>3), source chunk (t&7)^(row&7)
    const int srow = tid >> 3;              // 0..63
    const int schk = (tid & 7) ^ (srow & 7);
    const u16* aptr = A + (size_t)(m0 + srow) * KD + schk * 8;
    const u16* bptr = B + (size_t)(n0 + srow) * KD + schk * 8;
    const int lw = wave * 512;              // per-wave LDS deposit offset

    u16* const a0 = smem;          u16* const b0 = smem + 16384;
    u16* const a1 = smem + 32768;  u16* const b1 = smem + 49152;

    bf16x8 aF[4][2], bFa[2][2], bFb[2][2];
    const int NT = KD / 64;

    // half-tile stage: h=0 -> rows 0..127 (groups 0,1), h=1 -> rows 128..255
    #define STGA(d_, h_, k_) do { \
        gload16(aptr + (size_t)((h_) * 2 + 0) * 64 * KD + (k_), (d_) + ((h_) * 2 + 0) * 4096 + lw); \
        gload16(aptr + (size_t)((h_) * 2 + 1) * 64 * KD + (k_), (d_) + ((h_) * 2 + 1) * 4096 + lw); \
    } while (0)
    #define STGB(d_, h_, k_) do { \
        gload16(bptr + (size_t)((h_) * 2 + 0) * 64 * KD + (k_), (d_) + ((h_) * 2 + 0) * 4096 + lw); \
        gload16(bptr + (size_t)((h_) * 2 + 1) * 64 * KD + (k_), (d_) + ((h_) * 2 + 1) * 4096 + lw); \
    } while (0)

    // prologue: T0 complete (8 loads) + {B1h0, A1h0, A1h1} (6 loads);
    // vmcnt(6) drains the 8 T0 loads, leaves 3 half-tiles of T1 in flight.
    STGA(a0, 0, 0); STGA(a0, 1, 0);
    STGB(b0, 0, 0); STGB(b0, 1, 0);
    STGB(b1, 0, 64);
    STGA(a1, 0, 64); STGA(a1, 1, 64);
    WAITV(6);
    BARRIER();

    // per-tile body; cA_/cB_ = parity-u buffers, nB_ = parity-(u+1) B buffer
    #define TILE(u_, cA_, cB_, nB_) do { \
        /* P0: quad (0,0); stage B(u+1) half1 */ \
        ldA<0>(cA_, aBase, c0, c1, aF); \
        ldB<0>(cB_, bBase, c0, c1, bFa); \
        if ((u_) + 1 < NT) STGB(nB_, 1, ((u_) + 1) * 64); \
        BARRIER(); \
        doMFMA<0, 0>(aF, bFa, acc); \
        BARRIER(); \
        /* P1: quad (0,1) — reuse aF */ \
        ldB<1>(cB_, bBase, c0, c1, bFb); \
        BARRIER(); \
        doMFMA<0, 1>(aF, bFb, acc); \
        BARRIER(); \
        /* P2: quad (1,1) — reuse bFb; stage B(u+2) half0 (rows done at P1) */ \
        ldA<1>(cA_, aBase, c0, c1, aF); \
        if ((u_) + 2 < NT) STGB(cB_, 0, ((u_) + 2) * 64); \
        BARRIER(); \
        doMFMA<1, 1>(aF, bFb, acc); \
        BARRIER(); \
        /* P3: quad (1,0) — reuse aF + held bFa; stage A(u+2) both halves; */ \
        /* single counted wait: tile u+1 fully deposited, 6 loads in flight */ \
        if ((u_) + 2 < NT) { \
            STGA(cA_, 0, ((u_) + 2) * 64); \
            STGA(cA_, 1, ((u_) + 2) * 64); \
            WAITV(6); \
        } else { \
            WAITV(0); \
        } \
        BARRIER(); \
        doMFMA<1, 0>(aF, bFa, acc); \
        BARRIER(); \
    } while (0)

    for (int up = 0; up < NT / 2; ++up) {
        TILE(2 * up,     a0, b0, b1);
        TILE(2 * up + 1, a1, b1, b0);
    }
    #undef TILE
    #undef STGA
    #undef STGB
}

// ---------------------------------------------------------------------------
// Kernel: Bu = Ubf @ Bcomb^T  (M=16384, N=2048, K=1024), output bf16.
// Round-0 verified structure: 128x128 tile, 256 thr, 2048 blocks,
// XCD-banded decode, LDS repack epilogue -> coalesced 16B stores.
// ---------------------------------------------------------------------------
#define ST 136   // LDS repack row stride (u16): 272 B, 16B-aligned
__global__ __launch_bounds__(256) void gemm_bu_k(
    const u16* __restrict__ A, const u16* __restrict__ B, u16* __restrict__ O)
{
    __shared__ u16 smem[128 * ST];     // 34816 B; aliases sA|sB during K-loop
    u16* sA = smem;
    u16* sB = smem + 128 * 64;
    floatx4 acc[4][4] = {};
    const int d = blockIdx.x;
    const int xcd = d & 7, s = d >> 3;               // s: 0..255
    const int m0 = (xcd * 16 + (s >> 4)) * 128;      // m-tile band per XCD
    const int n0 = (s & 15) * 128;
    gemm_core128<HDIM>(A, B, m0, n0, sA, sB, acc);

    const int tid = threadIdx.x, wave = tid >> 6, lane = tid & 63;
    const int lrow = lane & 15, lq = lane >> 4;
    const int wm = (wave >> 1) * 64, wn = (wave & 1) * 64;

    // C tile -> LDS (row-major, stride ST)
    #pragma unroll
    for (int nt = 0; nt < 4; ++nt) {
        int col = wn + nt * 16 + lrow;
        #pragma unroll
        for (int mt = 0; mt < 4; ++mt)
            #pragma unroll
            for (int r = 0; r < 4; ++r) {
                int row = wm + mt * 16 + lq * 4 + r;
                smem[row * ST + col] = f2bf(acc[mt][nt][r]);
            }
    }
    __syncthreads();

    // coalesced store: thread t covers rows (t>>4)+16j, cols (t&15)*8..+7
    const int col = (tid & 15) * 8;
    const int rb  = tid >> 4;
    #pragma unroll
    for (int j = 0; j < 8; ++j) {
        int row = rb + j * 16;
        *(u16x8*)(O + (size_t)(m0 + row) * NBU + n0 + col) =
            *(const u16x8*)(smem + row * ST + col);
    }
}

// ---------------------------------------------------------------------------
// Kernel: out = Re(C x) + D.*u  (M=16384, N=1024, K=2048), output fp32.
// Deep-pipelined 256^2 core. Grid 256 blocks x 512 thr (1 block/CU).
// ---------------------------------------------------------------------------
__global__ __launch_bounds__(512, 2) void gemm_out_k(
    const u16* __restrict__ A, const u16* __restrict__ B,
    const float* __restrict__ Dv, const u16* __restrict__ Ubf,
    float* __restrict__ O)
{
    __shared__ __align__(16) u16 smem[65536];   // 128 KiB
    floatx4 acc[8][4] = {};
    const int d = blockIdx.x;
    const int xcd = d & 7, s = d >> 3;               // s: 0..31
    const int m0 = (xcd * 8 + (s >> 2)) * 256;
    const int n0 = (s & 3) * 256;
    gemm256_deep<NBU>(A, B, m0, n0, smem, acc);

    const int tid = threadIdx.x, wave = tid >> 6, lane = tid & 63;
    const int lrow = lane & 15, lq = lane >> 4;
    const int wm = wave >> 2, wn = wave & 3;
    #pragma unroll
    for (int nf = 0; nf < 4; ++nf) {
        int col = n0 + wn * 64 + nf * 16 + lrow;
        float dval = Dv[col];
        #pragma unroll
        for (int mf = 0; mf < 8; ++mf)
            #pragma unroll
            for (int r = 0; r < 4; ++r) {
                int row = m0 + wm * 128 + mf * 16 + lq * 4 + r;
                size_t o = (size_t)row * HDIM + col;
                O[o] = acc[mf][nf][r] + dval * bfu2f(Ubf[o]);
            }
    }
}

// ---------------------------------------------------------------------------
// Merged prep kernel (single launch): band 0 = U->bf16 (8192 blocks),
// band 1 = Bcomb (1024 blocks), band 2 = Bcbf (1024 blocks).
// ---------------------------------------------------------------------------
__global__ __launch_bounds__(256) void prep_all(
    const float* __restrict__ U, u16* __restrict__ Ubf,
    const float* __restrict__ Bre, const float* __restrict__ Bim,
    const float* __restrict__ gamma_log, u16* __restrict__ Bcomb,
    const float* __restrict__ Cre, const float* __restrict__ Cim,
    u16* __restrict__ Bcbf)
{
    const int bid = blockIdx.x;
    if (bid < 8192) {
        size_t i = ((size_t)bid * 256 + threadIdx.x) * 8;
        float4 a = *(const float4*)(U + i);
        float4 b = *(const float4*)(U + i + 4);
        u16x8 w;
        w[0]=f2bf(a.x); w[1]=f2bf(a.y); w[2]=f2bf(a.z); w[3]=f2bf(a.w);
        w[4]=f2bf(b.x); w[5]=f2bf(b.y); w[6]=f2bf(b.z); w[7]=f2bf(b.w);
        *(u16x8*)(Ubf + i) = w;
    } else if (bid < 9216) {
        int t = (bid - 8192) * 256 + threadIdx.x;      // 0 .. 262143
        int n = t >> 7;
        int h = (t & 127) * 8;
        int p = n >> 1, sflag = n & 1;
        const float* src = (sflag ? Bim : Bre) + (size_t)p * HDIM + h;
        float g = expf(gamma_log[p]);
        float4 a = *(const float4*)src;
        float4 b = *(const float4*)(src + 4);
        u16x8 w;
        w[0]=f2bf(a.x*g); w[1]=f2bf(a.y*g); w[2]=f2bf(a.z*g); w[3]=f2bf(a.w*g);
        w[4]=f2bf(b.x*g); w[5]=f2bf(b.y*g); w[6]=f2bf(b.z*g); w[7]=f2bf(b.w*g);
        *(u16x8*)(Bcomb + (size_t)n * HDIM + h) = w;
    } else {
        int t = (bid - 9216) * 256 + threadIdx.x;      // 0 .. 262143
        int h = t >> 8;
        int k = (t & 255) * 4;
        float4 cr = *(const float4*)(Cre + (size_t)h * PDIM + k);
        float4 ci = *(const float4*)(Cim + (size_t)h * PDIM + k);
        u16x8 w;
        w[0]=f2bf(cr.x); w[1]=f2bf(-ci.x);
        w[2]=f2bf(cr.y); w[3]=f2bf(-ci.y);
        w[4]=f2bf(cr.z); w[5]=f2bf(-ci.z);
        w[6]=f2bf(cr.w); w[7]=f2bf(-ci.w);
        *(u16x8*)(Bcbf + (size_t)h * NBU + 2 * k) = w;
    }
}

// ---------------------------------------------------------------------------
// Scan pass A: per-chunk local end states (bf16 Bu in, fp32 state out).
// ---------------------------------------------------------------------------
__global__ __launch_bounds__(256) void scan_passA(
    const uint32_t* __restrict__ BuC,
    const float* __restrict__ nu_log, const float* __restrict__ theta_log,
    float* __restrict__ endC)
{
    int tid = blockIdx.x * 256 + threadIdx.x;           // 0 .. 131071
    int p0 = (tid & 511) * 2;
    int c  = (tid >> 9) & (NCHUNK - 1);
    int b  = tid >> 15;
    float nu0 = expf(nu_log[p0]),     th0 = expf(theta_log[p0]);
    float nu1 = expf(nu_log[p0 + 1]), th1 = expf(theta_log[p0 + 1]);
    float el0 = expf(-nu0), el1 = expf(-nu1);
    float lr0 = el0 * cosf(th0), li0 = el0 * sinf(th0);
    float lr1 = el1 * cosf(th1), li1 = el1 * sinf(th1);
    const uint32_t* src = BuC + (size_t)(b * LSEQ + c * CHUNK) * PDIM + p0;
    float xr0 = 0.f, xi0 = 0.f, xr1 = 0.f, xi1 = 0.f;
    #pragma unroll 8
    for (int t = 0; t < CHUNK; ++t) {
        uint2 v = *(const uint2*)(src + (size_t)t * PDIM);
        float br0 = bfu2f(v.x & 0xffffu), bi0 = bfu2f(v.x >> 16);
        float br1 = bfu2f(v.y & 0xffffu), bi1 = bfu2f(v.y >> 16);
        float nr0 = fmaf(lr0, xr0, fmaf(-li0, xi0, br0));
        float ni0 = fmaf(lr0, xi0, fmaf(li0, xr0, bi0));
        float nr1 = fmaf(lr1, xr1, fmaf(-li1, xi1, br1));
        float ni1 = fmaf(lr1, xi1, fmaf(li1, xr1, bi1));
        xr0 = nr0; xi0 = ni0; xr1 = nr1; xi1 = ni1;
    }
    float4 e; e.x = xr0; e.y = xi0; e.z = xr1; e.w = xi1;
    *(float4*)(endC + (((size_t)b * NCHUNK + c) * PDIM + p0) * 2) = e;
}

// ---------------------------------------------------------------------------
// Scan pass B: carry prefix across chunks.
// ---------------------------------------------------------------------------
__global__ __launch_bounds__(256) void scan_passB(
    const float* __restrict__ endC,
    const float* __restrict__ nu_log, const float* __restrict__ theta_log,
    float* __restrict__ carryC)
{
    int tid = blockIdx.x * 256 + threadIdx.x;           // 0 .. 2047
    int p0 = (tid & 511) * 2;
    int b  = tid >> 9;
    float nu0 = expf(nu_log[p0]),     th0 = expf(theta_log[p0]);
    float nu1 = expf(nu_log[p0 + 1]), th1 = expf(theta_log[p0 + 1]);
    float e0 = expf(-nu0 * (float)CHUNK), a0 = th0 * (float)CHUNK;
    float e1 = expf(-nu1 * (float)CHUNK), a1 = th1 * (float)CHUNK;
    float Lr0 = e0 * cosf(a0), Li0 = e0 * sinf(a0);
    float Lr1 = e1 * cosf(a1), Li1 = e1 * sinf(a1);
    float gr0 = 0.f, gi0 = 0.f, gr1 = 0.f, gi1 = 0.f;
    for (int g = 0; g < 8; ++g) {
        float4 e[8];
        #pragma unroll
        for (int j = 0; j < 8; ++j)
            e[j] = *(const float4*)(endC + (((size_t)b * NCHUNK + g * 8 + j) * PDIM + p0) * 2);
        #pragma unroll
        for (int j = 0; j < 8; ++j) {
            size_t idx = (((size_t)b * NCHUNK + g * 8 + j) * PDIM + p0) * 2;
            float4 go; go.x = gr0; go.y = gi0; go.z = gr1; go.w = gi1;
            *(float4*)(carryC + idx) = go;
            float nr0 = fmaf(Lr0, gr0, fmaf(-Li0, gi0, e[j].x));
            float ni0 = fmaf(Lr0, gi0, fmaf(Li0, gr0, e[j].y));
            float nr1 = fmaf(Lr1, gr1, fmaf(-Li1, gi1, e[j].z));
            float ni1 = fmaf(Lr1, gi1, fmaf(Li1, gr1, e[j].w));
            gr0 = nr0; gi0 = ni0; gr1 = nr1; gi1 = ni1;
        }
    }
}

// ---------------------------------------------------------------------------
// Scan pass C: re-scan each chunk from its entering state; x in place.
// ---------------------------------------------------------------------------
__global__ __launch_bounds__(256) void scan_passC(
    uint32_t* __restrict__ BuC,
    const float* __restrict__ nu_log, const float* __restrict__ theta_log,
    const float* __restrict__ carryC)
{
    int tid = blockIdx.x * 256 + threadIdx.x;           // 0 .. 131071
    int p0 = (tid & 511) * 2;
    int c  = (tid >> 9) & (NCHUNK - 1);
    int b  = tid >> 15;
    float nu0 = expf(nu_log[p0]),     th0 = expf(theta_log[p0]);
    float nu1 = expf(nu_log[p0 + 1]), th1 = expf(theta_log[p0 + 1]);
    float el0 = expf(-nu0), el1 = expf(-nu1);
    float lr0 = el0 * cosf(th0), li0 = el0 * sinf(th0);
    float lr1 = el1 * cosf(th1), li1 = el1 * sinf(th1);
    float4 g = *(const float4*)(carryC + (((size_t)b * NCHUNK + c) * PDIM + p0) * 2);
    float xr0 = g.x, xi0 = g.y, xr1 = g.z, xi1 = g.w;
    uint32_t* ptr = BuC + (size_t)(b * LSEQ + c * CHUNK) * PDIM + p0;
    #pragma unroll 8
    for (int t = 0; t < CHUNK; ++t) {
        uint32_t* q = ptr + (size_t)t * PDIM;
        uint2 v = *(const uint2*)q;
        float br0 = bfu2f(v.x & 0xffffu), bi0 = bfu2f(v.x >> 16);
        float br1 = bfu2f(v.y & 0xffffu), bi1 = bfu2f(v.y >> 16);
        float nr0 = fmaf(lr0, xr0, fmaf(-li0, xi0, br0));
        float ni0 = fmaf(lr0, xi0, fmaf(li0, xr0, bi0));
        float nr1 = fmaf(lr1, xr1, fmaf(-li1, xi1, br1));
        float ni1 = fmaf(lr1, xi1, fmaf(li1, xr1, bi1));
        xr0 = nr0; xi0 = ni0; xr1 = nr1; xi1 = ni1;
        uint2 o;
        o.x = (uint32_t)f2bf(xr0) | ((uint32_t)f2bf(xi0) << 16);
        o.y = (uint32_t)f2bf(xr1) | ((uint32_t)f2bf(xi1) << 16);
        *(uint2*)q = o;
    }
}

// ---------------------------------------------------------------------------
extern "C" void kernel_launch(void* const* d_in, const int* in_sizes, int n_in,
                              void* d_out, int out_size, void* d_ws, size_t ws_size,
                              hipStream_t stream)
{
    (void)in_sizes; (void)n_in; (void)out_size; (void)ws_size;
    const float* U         = (const float*)d_in[0];
    const float* nu_log    = (const float*)d_in[1];
    const float* theta_log = (const float*)d_in[2];
    const float* B_re      = (const float*)d_in[3];
    const float* B_im      = (const float*)d_in[4];
    const float* C_re      = (const float*)d_in[5];
    const float* C_im      = (const float*)d_in[6];
    const float* Dv        = (const float*)d_in[7];
    const float* gamma_log = (const float*)d_in[8];
    float* out = (float*)d_out;

    // workspace layout (bytes), 256B aligned
    char* ws = (char*)d_ws;
    u16*   BuC    = (u16*)ws;                                   // 64 MB
    u16*   Ubf    = (u16*)(ws + (size_t)64 * 1024 * 1024);      // 32 MB
    u16*   Bcomb  = (u16*)(ws + (size_t)96 * 1024 * 1024);      // 4 MB
    u16*   Bcbf   = (u16*)(ws + (size_t)100 * 1024 * 1024);     // 4 MB
    float* endC   = (float*)(ws + (size_t)104 * 1024 * 1024);   // 2 MB
    float* carryC = (float*)(ws + (size_t)106 * 1024 * 1024);   // 2 MB

    prep_all<<<8192 + 1024 + 1024, 256, 0, stream>>>(
        U, Ubf, B_re, B_im, gamma_log, Bcomb, C_re, C_im, Bcbf);

    gemm_bu_k<<<2048, 256, 0, stream>>>(Ubf, Bcomb, BuC);

    scan_passA<<<(BSZ * NCHUNK * PDIM / 2) / 256, 256, 0, stream>>>(
        (const uint32_t*)BuC, nu_log, theta_log, endC);
    scan_passB<<<(BSZ * PDIM / 2) / 256, 256, 0, stream>>>(endC, nu_log, theta_log, carryC);
    scan_passC<<<(BSZ * NCHUNK * PDIM / 2) / 256, 256, 0, stream>>>(
        (uint32_t*)BuC, nu_log, theta_log, carryC);

    gemm_out_k<<<256, 512, 0, stream>>>(BuC, Bcbf, Dv, Ubf, out);
}